// Round 1
// baseline (272.357 us; speedup 1.0000x reference)
//
#include <hip/hip_runtime.h>
#include <hip/hip_fp16.h>

#define NN 65536
#define EE 524288
#define CC 128
#define CAP 32   // max in-degree bucket; P(deg>32) ~ 2e-11 per node at lambda=8 (guarded anyway)

typedef _Float16 f16x8 __attribute__((ext_vector_type(8)));
typedef float f32x4 __attribute__((ext_vector_type(4)));

// ---------- phase 0: convert + stats (blocks 0..255) | bucket scatter (blocks 256..767) ----------

__global__ void k_init(const float* __restrict__ x, __half* __restrict__ h,
                       float* __restrict__ pstat0,
                       const int* __restrict__ src, const int* __restrict__ dst,
                       const float* __restrict__ ew,
                       int* __restrict__ cnt, unsigned int* __restrict__ buf) {
    int b = blockIdx.x, t = threadIdx.x;
    if (b < 256) {
        // fp32 -> fp16 convert + layer-0 BN stats on fp32 values
        const float4* xv = (const float4*)x;
        __half2* o = (__half2*)h;
        float s[4] = {0, 0, 0, 0}, q[4] = {0, 0, 0, 0};
        for (int k = 0; k < 32; k++) {
            int i = b * 8192 + k * 256 + t;
            float4 v = xv[i];
            o[2 * i]     = __floats2half2_rn(v.x, v.y);
            o[2 * i + 1] = __floats2half2_rn(v.z, v.w);
            s[0] += v.x; s[1] += v.y; s[2] += v.z; s[3] += v.w;
            q[0] += v.x * v.x; q[1] += v.y * v.y; q[2] += v.z * v.z; q[3] += v.w * v.w;
        }
        __shared__ float ls[256];          // [0..127] sum, [128..255] sumsq
        ls[t] = 0.f;
        __syncthreads();
        int c0 = (t & 31) * 4;
#pragma unroll
        for (int u = 0; u < 4; u++) {
            atomicAdd(&ls[c0 + u], s[u]);
            atomicAdd(&ls[128 + c0 + u], q[u]);
        }
        __syncthreads();
        if (t < 128) {
            atomicAdd(&pstat0[t], ls[t]);
            atomicAdd(&pstat0[128 + t], ls[128 + t]);
        }
    } else {
        // bucket-CSR build: 4 edges per thread, loads/atomics/stores batched per class
        // so 4 independent atomic chains are in flight per thread (MLP=4).
        int base = (b - 256) * 1024 + t;
        int dd[4], sr[4];
        float we[4];
#pragma unroll
        for (int u = 0; u < 4; u++) dd[u] = dst[base + u * 256];
#pragma unroll
        for (int u = 0; u < 4; u++) sr[u] = src[base + u * 256];
#pragma unroll
        for (int u = 0; u < 4; u++) we[u] = ew[base + u * 256];
        int pos[4];
#pragma unroll
        for (int u = 0; u < 4; u++) pos[u] = atomicAdd(&cnt[dd[u]], 1);
#pragma unroll
        for (int u = 0; u < 4; u++) {
            float w = log1pf(we[u]);
            unsigned int pk = (unsigned int)sr[u] |
                              ((unsigned int)__half_as_ushort(__float2half(w)) << 16);
            if (pos[u] < CAP) buf[dd[u] * CAP + pos[u]] = pk;   // guard: never corrupt memory
        }
    }
}

// ---------- per-layer: agg (blocks 0..NN/8-1, 2 nodes/wave) | BN-fold (last 64 blocks) ----------

__global__ void k_aggfold(const __half2* __restrict__ h, const int* __restrict__ cnt,
                          const unsigned int* __restrict__ buf,
                          __half2* __restrict__ aggn, float* __restrict__ sod, int writeSod,
                          const float* __restrict__ pstat_l,
                          const float* __restrict__ gamma, const float* __restrict__ beta,
                          const float* __restrict__ Ws, const float* __restrict__ Wn,
                          const float* __restrict__ bias,
                          __half* __restrict__ Wcat, float* __restrict__ crow,
                          float* __restrict__ cneigh) {
    int bid = blockIdx.x;
    int tid = threadIdx.x;
    if (bid >= NN / 8) {
        // ---- fold: 2 output channels per block, k = tid & 127 ----
        int c = (bid - NN / 8) * 2 + (tid >> 7);
        int k = tid & 127;
        float mu = pstat_l[k] * (1.0f / NN);
        float var = pstat_l[128 + k] * (1.0f / NN) - mu * mu;
        float alpha = rsqrtf(var + 1e-5f) * gamma[k];
        float delta = beta[k] - mu * alpha;
        float ws = Ws[k * 128 + c];
        float wn = Wn[k * 128 + c];
        Wcat[c * 256 + k]       = __float2half(alpha * ws);   // self path
        Wcat[c * 256 + 128 + k] = __float2half(alpha * wn);   // neigh path
        float rs = delta * ws, rn = delta * wn;
#pragma unroll
        for (int off = 1; off < 64; off <<= 1) {
            rs += __shfl_xor(rs, off);
            rn += __shfl_xor(rn, off);
        }
        __shared__ float tmp[8];
        int wv = tid >> 6;                 // wave 0..3
        if ((tid & 63) == 0) { tmp[wv * 2] = rs; tmp[wv * 2 + 1] = rn; }
        __syncthreads();
        if ((tid & 127) == 0) {            // tid 0 (c lower) and 128 (c upper)
            int base = (tid >> 7) * 4;
            crow[c]   = bias[c] + tmp[base + 0] + tmp[base + 2];
            cneigh[c] = tmp[base + 1] + tmp[base + 3];
        }
        return;
    }
    // ---- aggregate: TWO nodes per wave -> up to 16 row-gathers in flight ----
    int lane = tid & 63;
    int n0 = bid * 8 + (tid >> 6) * 2;
    int n1 = n0 + 1;
    int dA = cnt[n0]; if (dA > CAP) dA = CAP;
    int dB = cnt[n1]; if (dB > CAP) dB = CAP;
    unsigned int pkA = 0, pkB = 0;         // lanes >= d: src=0, w=+0 -> no-op contribution
    if (lane < dA) pkA = buf[n0 * CAP + lane];
    if (lane < dB) pkB = buf[n1 * CAP + lane];
    float ax[8], ay[8], bx[8], by[8];
#pragma unroll
    for (int u = 0; u < 8; u++) { ax[u] = 0.f; ay[u] = 0.f; bx[u] = 0.f; by[u] = 0.f; }
    int dmax = dA > dB ? dA : dB;
    int rounds = (dmax + 7) >> 3;
    for (int r = 0; r < rounds; r++) {
        int j = r * 8;
        unsigned int pA[8], pB[8];
        __half2 hA[8], hB[8];
#pragma unroll
        for (int u = 0; u < 8; u++) pA[u] = __shfl(pkA, j + u);
#pragma unroll
        for (int u = 0; u < 8; u++) pB[u] = __shfl(pkB, j + u);
#pragma unroll
        for (int u = 0; u < 8; u++) hA[u] = h[(pA[u] & 0xFFFF) * 64 + lane];
#pragma unroll
        for (int u = 0; u < 8; u++) hB[u] = h[(pB[u] & 0xFFFF) * 64 + lane];
#pragma unroll
        for (int u = 0; u < 8; u++) {
            float w = __half2float(__ushort_as_half((unsigned short)(pA[u] >> 16)));
            float2 v = __half22float2(hA[u]);
            ax[u] += w * v.x;
            ay[u] += w * v.y;
        }
#pragma unroll
        for (int u = 0; u < 8; u++) {
            float w = __half2float(__ushort_as_half((unsigned short)(pB[u] >> 16)));
            float2 v = __half22float2(hB[u]);
            bx[u] += w * v.x;
            by[u] += w * v.y;
        }
    }
    float axs = ((ax[0] + ax[1]) + (ax[2] + ax[3])) + ((ax[4] + ax[5]) + (ax[6] + ax[7]));
    float ays = ((ay[0] + ay[1]) + (ay[2] + ay[3])) + ((ay[4] + ay[5]) + (ay[6] + ay[7]));
    float bxs = ((bx[0] + bx[1]) + (bx[2] + bx[3])) + ((bx[4] + bx[5]) + (bx[6] + bx[7]));
    float bys = ((by[0] + by[1]) + (by[2] + by[3])) + ((by[4] + by[5]) + (by[6] + by[7]));
    float invA = 1.0f / (float)(dA > 1 ? dA : 1);
    float invB = 1.0f / (float)(dB > 1 ? dB : 1);
    aggn[n0 * 64 + lane] = __floats2half2_rn(axs * invA, ays * invA);
    aggn[n1 * 64 + lane] = __floats2half2_rn(bxs * invB, bys * invB);
    if (writeSod) {
        float wA = __half2float(__ushort_as_half((unsigned short)(pkA >> 16)));
        float wB = __half2float(__ushort_as_half((unsigned short)(pkB >> 16)));
#pragma unroll
        for (int off = 1; off < 64; off <<= 1) {
            wA += __shfl_xor(wA, off);
            wB += __shfl_xor(wB, off);
        }
        if (lane == 0) { sod[n0] = wA * invA; sod[n1] = wB * invB; }
    }
}

// ---------- fused dual-GEMM: relu([h | aggn] @ [Ws'; Wn'] + crow + sod*cneigh) ----------
// IN PLACE: hout == hA is safe (each block reads its rows fully before writing).
// mode 0: write fp16 h_next + accumulate next-layer BN stats into pstatN
// mode 1: dot rows with lin_w -> out (fp32)
__launch_bounds__(256, 2)
__global__ void k_gemm(const __half* hA, const __half* __restrict__ aggn,
                       const __half* __restrict__ Wcat,
                       const float* __restrict__ crow, const float* __restrict__ cneigh,
                       const float* __restrict__ sod,
                       const float* __restrict__ lin_w, const float* __restrict__ lin_b,
                       __half* hout, float* __restrict__ outv, int mode,
                       float* __restrict__ pstatN) {
    __shared__ __half Bl[128 * 136];   // [c][k_local], stride 136 halves
    int tid = threadIdx.x;
    int lane = tid & 63;
    int wvid = tid >> 6;               // wave 0..3 -> rows [wvid*32, wvid*32+32)
    int l15 = lane & 15, quad = lane >> 4;
    int i0 = blockIdx.x * 128;

    f32x4 acc0[8], acc1[8];
    f32x4 zero = {0.f, 0.f, 0.f, 0.f};
#pragma unroll
    for (int t = 0; t < 8; t++) { acc0[t] = zero; acc1[t] = zero; }

#pragma unroll
    for (int chunk = 0; chunk < 2; chunk++) {
        const __half* Asrc = chunk ? aggn : hA;
        f16x8 af0[4], af1[4];
#pragma unroll
        for (int s = 0; s < 4; s++) {
            int kof = s * 32 + quad * 8;
            af0[s] = *(const f16x8*)&Asrc[(i0 + wvid * 32 + l15) * 128 + kof];
            af1[s] = *(const f16x8*)&Asrc[(i0 + wvid * 32 + 16 + l15) * 128 + kof];
        }
        __syncthreads();   // previous chunk's reads of Bl done
#pragma unroll
        for (int it = 0; it < 8; it++) {
            int m = tid * 8 + it * 2048;         // covers 128x128 chunk
            int c = m >> 7, kl = m & 127;
            *(f16x8*)&Bl[c * 136 + kl] = *(const f16x8*)&Wcat[c * 256 + chunk * 128 + kl];
        }
        __syncthreads();
#pragma unroll
        for (int s = 0; s < 4; s++) {
#pragma unroll
            for (int tn = 0; tn < 8; tn++) {
                f16x8 bf = *(const f16x8*)&Bl[(tn * 16 + l15) * 136 + s * 32 + quad * 8];
                acc0[tn] = __builtin_amdgcn_mfma_f32_16x16x32_f16(af0[s], bf, acc0[tn], 0, 0, 0);
                acc1[tn] = __builtin_amdgcn_mfma_f32_16x16x32_f16(af1[s], bf, acc1[tn], 0, 0, 0);
            }
        }
    }

    float cr[8], cn[8];
#pragma unroll
    for (int tn = 0; tn < 8; tn++) {
        cr[tn] = crow[tn * 16 + l15];
        cn[tn] = cneigh[tn * 16 + l15];
    }
    int rwbase = i0 + wvid * 32 + quad * 4;

    if (mode == 0) {
        float cs[8], cq[8];
#pragma unroll
        for (int tn = 0; tn < 8; tn++) { cs[tn] = 0.f; cq[tn] = 0.f; }
#pragma unroll
        for (int tm = 0; tm < 2; tm++) {
#pragma unroll
            for (int r = 0; r < 4; r++) {
                int row = rwbase + tm * 16 + r;
                float sdv = sod[row];
#pragma unroll
                for (int tn = 0; tn < 8; tn++) {
                    float v = (tm ? acc1[tn][r] : acc0[tn][r]) + cr[tn] + sdv * cn[tn];
                    v = fmaxf(v, 0.f);
                    hout[row * 128 + tn * 16 + l15] = __float2half(v);
                    cs[tn] += v;
                    cq[tn] += v * v;
                }
            }
        }
        // reduce stats across quads within wave, then LDS across waves, then global
#pragma unroll
        for (int tn = 0; tn < 8; tn++) {
            cs[tn] += __shfl_xor(cs[tn], 16); cs[tn] += __shfl_xor(cs[tn], 32);
            cq[tn] += __shfl_xor(cq[tn], 16); cq[tn] += __shfl_xor(cq[tn], 32);
        }
        __syncthreads();
        float* st = (float*)Bl;            // reuse LDS: [0..127] sum, [128..255] sumsq
        st[tid] = 0.f;
        __syncthreads();
        if (lane < 16) {
#pragma unroll
            for (int tn = 0; tn < 8; tn++) {
                atomicAdd(&st[tn * 16 + l15], cs[tn]);
                atomicAdd(&st[128 + tn * 16 + l15], cq[tn]);
            }
        }
        __syncthreads();
        if (tid < 128) {
            atomicAdd(&pstatN[tid], st[tid]);
            atomicAdd(&pstatN[128 + tid], st[128 + tid]);
        }
    } else {
        float lw[8];
#pragma unroll
        for (int tn = 0; tn < 8; tn++) lw[tn] = lin_w[tn * 16 + l15];
        float lb = lin_b[0];
#pragma unroll
        for (int tm = 0; tm < 2; tm++) {
#pragma unroll
            for (int r = 0; r < 4; r++) {
                int row = rwbase + tm * 16 + r;
                float sdv = sod[row];
                float p = 0.f;
#pragma unroll
                for (int tn = 0; tn < 8; tn++) {
                    float v = (tm ? acc1[tn][r] : acc0[tn][r]) + cr[tn] + sdv * cn[tn];
                    v = fmaxf(v, 0.f);
                    p += v * lw[tn];
                }
                p += __shfl_xor(p, 1);
                p += __shfl_xor(p, 2);
                p += __shfl_xor(p, 4);
                p += __shfl_xor(p, 8);
                if (l15 == 0) outv[row] = p + lb;
            }
        }
    }
}

// ---------- host ----------

extern "C" void kernel_launch(void* const* d_in, const int* in_sizes, int n_in,
                              void* d_out, int out_size, void* d_ws, size_t ws_size,
                              hipStream_t stream) {
    (void)in_sizes; (void)n_in; (void)out_size; (void)ws_size;
    const float* x     = (const float*)d_in[0];
    const float* ew    = (const float*)d_in[1];
    const float* gamma = (const float*)d_in[2];
    const float* beta  = (const float*)d_in[3];
    const float* Ws    = (const float*)d_in[4];
    const float* Wn    = (const float*)d_in[5];
    const float* bias  = (const float*)d_in[6];
    const float* lin_w = (const float*)d_in[7];
    const float* lin_b = (const float*)d_in[8];
    const int*   srcI  = (const int*)d_in[9];
    const int*   dstI  = (const int*)d_in[10];
    float* out = (float*)d_out;

    char* p = (char*)d_ws;
    __half* h    = (__half*)p; p += (size_t)NN * CC * 2;   // in-place across layers
    __half* aggn = (__half*)p; p += (size_t)NN * CC * 2;
    __half* Wcat = (__half*)p; p += 256 * 128 * 2;
    float* crow   = (float*)p; p += 512;
    float* cneigh = (float*)p; p += 512;
    float* sod    = (float*)p; p += (size_t)NN * 4;
    unsigned int* buf = (unsigned int*)p; p += (size_t)NN * CAP * 4;
    // ---- contiguous zero region ----
    int*   cnt    = (int*)p;   p += (size_t)NN * 4;
    float* pstat  = (float*)p; p += 3 * 256 * 4;     // [layer][sum(128)|sumsq(128)]

    hipMemsetAsync(cnt, 0, (size_t)NN * 4 + 3 * 256 * 4, stream);

    k_init<<<dim3(256 + EE / 1024), dim3(256), 0, stream>>>(x, h, pstat, srcI, dstI, ew, cnt, buf);

    for (int l = 0; l < 3; l++) {
        k_aggfold<<<dim3(NN / 8 + 64), dim3(256), 0, stream>>>(
            (const __half2*)h, cnt, buf, (__half2*)aggn, sod, (l == 0) ? 1 : 0,
            pstat + l * 256, gamma + l * CC, beta + l * CC,
            Ws + (size_t)l * CC * CC, Wn + (size_t)l * CC * CC, bias + l * CC,
            Wcat, crow, cneigh);
        int mode = (l == 2) ? 1 : 0;
        float* pstatN = (mode == 0) ? (pstat + (l + 1) * 256) : pstat;
        k_gemm<<<dim3(NN / 128), dim3(256), 0, stream>>>(h, aggn, Wcat, crow, cneigh, sod,
                                                         lin_w, lin_b, h, out, mode, pstatN);
    }
}